// Round 12
// baseline (871.601 us; speedup 1.0000x reference)
//
#include <hip/hip_runtime.h>
#include <stdint.h>

#define DEV __device__ __forceinline__

typedef __attribute__((ext_vector_type(8))) short short8;
typedef __attribute__((ext_vector_type(8))) __bf16 bf16x8;
typedef __attribute__((ext_vector_type(4))) float f32x4;

DEV unsigned short f2bf(float f) {
  union { float f; unsigned int u; } v; v.f = f;
  unsigned int r = v.u + 0x7fffu + ((v.u >> 16) & 1u);
  return (unsigned short)(r >> 16);
}
DEV float bf2f(unsigned short h) {
  union { unsigned int u; float f; } v; v.u = ((unsigned int)h) << 16;
  return v.f;
}
DEV f32x4 mfma16(short8 a, short8 b, f32x4 c) {
  return __builtin_amdgcn_mfma_f32_16x16x32_bf16(
      __builtin_bit_cast(bf16x8, a), __builtin_bit_cast(bf16x8, b), c, 0, 0, 0);
}
DEV void gload_lds16(const void* g, void* lds) {
  __builtin_amdgcn_global_load_lds(
      (const __attribute__((address_space(1))) void*)g,
      (__attribute__((address_space(3))) void*)lds, 16, 0, 0);
}

struct MArgs {
  const float* src[7];
  unsigned short* dst[7];
  int n[7];
  int sidx[7];
};

// ---------------- abs-mean partial (all matrices, one launch) ----------------
__global__ __launch_bounds__(256) void absmean_partial_multi(
    MArgs a, float* __restrict__ partial) {
  const int m = blockIdx.y;
  const float4* w4 = (const float4*)a.src[m];
  const int n4 = a.n[m] >> 2;
  float s = 0.f;
  for (int i = blockIdx.x * 256 + threadIdx.x; i < n4; i += 1024 * 256) {
    float4 v = w4[i];
    s += fabsf(v.x) + fabsf(v.y) + fabsf(v.z) + fabsf(v.w);
  }
#pragma unroll
  for (int mm = 1; mm < 64; mm <<= 1) s += __shfl_xor(s, mm);
  __shared__ float red[4];
  if ((threadIdx.x & 63) == 0) red[threadIdx.x >> 6] = s;
  __syncthreads();
  if (threadIdx.x == 0)
    partial[m * 1024 + blockIdx.x] = red[0] + red[1] + red[2] + red[3];
}

__global__ __launch_bounds__(256) void absmean_final(
    const float* __restrict__ partial, float* __restrict__ scales) {
  __shared__ double red[256];
  const int m = blockIdx.x;
  double s = 0.0;
  for (int i = threadIdx.x; i < 1024; i += 256) s += (double)partial[m * 1024 + i];
  red[threadIdx.x] = s;
  __syncthreads();
  for (int t = 128; t > 0; t >>= 1) {
    if (threadIdx.x < t) red[threadIdx.x] += red[threadIdx.x + t];
    __syncthreads();
  }
  if (threadIdx.x == 0) {
    const long long cnt = (m < 4) ? 4194304ll : 16777216ll;
    scales[m] = (float)(red[0] / (double)cnt);
  }
}

// ---------------- ternary quantize -> bf16 (batched) ----------------
__global__ __launch_bounds__(256) void quantize_multi(
    MArgs a, const float* __restrict__ scales) {
  const int m = blockIdx.y;
  const float sc = scales[a.sidx[m]];
  const float inv = 1.f / (sc + 1e-5f);
  const float4* src = (const float4*)a.src[m];
  ushort4* dst = (ushort4*)a.dst[m];
  const int n4 = a.n[m] >> 2;
  for (int i = blockIdx.x * 256 + threadIdx.x; i < n4; i += 2048 * 256) {
    float4 v = src[i];
    ushort4 o;
    o.x = f2bf(fminf(fmaxf(rintf(v.x * inv), -1.f), 1.f) * sc);
    o.y = f2bf(fminf(fmaxf(rintf(v.y * inv), -1.f), 1.f) * sc);
    o.z = f2bf(fminf(fmaxf(rintf(v.z * inv), -1.f), 1.f) * sc);
    o.w = f2bf(fminf(fmaxf(rintf(v.w * inv), -1.f), 1.f) * sc);
    dst[i] = o;
  }
}

// ---------------- RMSNorm (f32 in -> bf16 out) ----------------
__global__ __launch_bounds__(256) void rmsnorm_k(
    const float* __restrict__ x, const float* __restrict__ wt,
    unsigned short* __restrict__ out) {
  const long long t = blockIdx.x;
  const float* xr = x + t * 2048;
  const int i0 = threadIdx.x * 8;
  float4 a = *(const float4*)(xr + i0);
  float4 b = *(const float4*)(xr + i0 + 4);
  float ss = a.x * a.x + a.y * a.y + a.z * a.z + a.w * a.w +
             b.x * b.x + b.y * b.y + b.z * b.z + b.w * b.w;
#pragma unroll
  for (int m = 1; m < 64; m <<= 1) ss += __shfl_xor(ss, m);
  __shared__ float red[4];
  if ((threadIdx.x & 63) == 0) red[threadIdx.x >> 6] = ss;
  __syncthreads();
  float tot = red[0] + red[1] + red[2] + red[3];
  float rs = rsqrtf(tot * (1.f / 2048.f) + 1e-5f);
  float4 wa = *(const float4*)(wt + i0);
  float4 wb = *(const float4*)(wt + i0 + 4);
  ushort4 o1, o2;
  o1.x = f2bf(a.x * wa.x * rs); o1.y = f2bf(a.y * wa.y * rs);
  o1.z = f2bf(a.z * wa.z * rs); o1.w = f2bf(a.w * wa.w * rs);
  o2.x = f2bf(b.x * wb.x * rs); o2.y = f2bf(b.y * wb.y * rs);
  o2.z = f2bf(b.z * wb.z * rs); o2.w = f2bf(b.w * wb.w * rs);
  *(ushort4*)(out + t * 2048 + i0) = o1;
  *(ushort4*)(out + t * 2048 + i0 + 4) = o2;
}

// ---- fused O-combine + RMSNorm(ln2), bf16 split-K partials ----
__global__ __launch_bounds__(256) void combine_rms(
    const float* __restrict__ ep, const unsigned short* __restrict__ p,
    const float* __restrict__ wt, float* __restrict__ hout,
    unsigned short* __restrict__ yout) {
  const long long t = blockIdx.x;
  const int i0 = threadIdx.x * 8;
  const long long base = t * 2048 + i0;
  float4 e1 = *(const float4*)(ep + base);
  float4 e2 = *(const float4*)(ep + base + 4);
  short8 pa = *(const short8*)(p + base);
  short8 pb = *(const short8*)(p + 8388608 + base);
  const float e[8] = {e1.x, e1.y, e1.z, e1.w, e2.x, e2.y, e2.z, e2.w};
  float h[8];
#pragma unroll
  for (int i = 0; i < 8; ++i)
    h[i] = e[i] + bf2f((unsigned short)pa[i]) + bf2f((unsigned short)pb[i]);
  float4 h1 = {h[0], h[1], h[2], h[3]};
  float4 h2 = {h[4], h[5], h[6], h[7]};
  *(float4*)(hout + base) = h1;
  *(float4*)(hout + base + 4) = h2;
  float ss = 0.f;
#pragma unroll
  for (int i = 0; i < 8; ++i) ss += h[i] * h[i];
#pragma unroll
  for (int m = 1; m < 64; m <<= 1) ss += __shfl_xor(ss, m);
  __shared__ float red[4];
  if ((threadIdx.x & 63) == 0) red[threadIdx.x >> 6] = ss;
  __syncthreads();
  const float tot = red[0] + red[1] + red[2] + red[3];
  const float rs = rsqrtf(tot * (1.f / 2048.f) + 1e-5f);
  float4 wa = *(const float4*)(wt + i0);
  float4 wb = *(const float4*)(wt + i0 + 4);
  ushort4 o1, o2;
  o1.x = f2bf(h[0] * wa.x * rs); o1.y = f2bf(h[1] * wa.y * rs);
  o1.z = f2bf(h[2] * wa.z * rs); o1.w = f2bf(h[3] * wa.w * rs);
  o2.x = f2bf(h[4] * wb.x * rs); o2.y = f2bf(h[5] * wb.y * rs);
  o2.z = f2bf(h[6] * wb.z * rs); o2.w = f2bf(h[7] * wb.w * rs);
  *(ushort4*)(yout + base) = o1;
  *(ushort4*)(yout + base + 4) = o2;
}

// ---- D-combine, bf16 partials: out = ep + p0 + p1 ----
__global__ __launch_bounds__(256) void combine2(
    const float* __restrict__ ep, const unsigned short* __restrict__ p,
    float* __restrict__ out) {
  const long long base = (long long)blockIdx.x * 2048 + threadIdx.x * 8;
  float4 e1 = *(const float4*)(ep + base);
  float4 e2 = *(const float4*)(ep + base + 4);
  short8 pa = *(const short8*)(p + base);
  short8 pb = *(const short8*)(p + 8388608 + base);
  float4 o1, o2;
  o1.x = e1.x + bf2f((unsigned short)pa[0]) + bf2f((unsigned short)pb[0]);
  o1.y = e1.y + bf2f((unsigned short)pa[1]) + bf2f((unsigned short)pb[1]);
  o1.z = e1.z + bf2f((unsigned short)pa[2]) + bf2f((unsigned short)pb[2]);
  o1.w = e1.w + bf2f((unsigned short)pa[3]) + bf2f((unsigned short)pb[3]);
  o2.x = e2.x + bf2f((unsigned short)pa[4]) + bf2f((unsigned short)pb[4]);
  o2.y = e2.y + bf2f((unsigned short)pa[5]) + bf2f((unsigned short)pb[5]);
  o2.z = e2.z + bf2f((unsigned short)pa[6]) + bf2f((unsigned short)pb[6]);
  o2.w = e2.w + bf2f((unsigned short)pa[7]) + bf2f((unsigned short)pb[7]);
  *(float4*)(out + base) = o1;
  *(float4*)(out + base + 4) = o2;
}

// ---------------- RoPE (q,k only; V handled by vtrans_k) ----------------
__global__ __launch_bounds__(256) void rope_k(
    const unsigned short* __restrict__ qkv, const float* __restrict__ cosT,
    const float* __restrict__ sinT, unsigned short* __restrict__ qr,
    unsigned short* __restrict__ kr) {
  const long long gid = (long long)blockIdx.x * 256 + threadIdx.x;
  const int t = (int)(gid >> 10);
  const int r = (int)(gid & 1023);
  const int h = r >> 6, d = r & 63;
  const int s = t & 2047;
  const unsigned short* row = qkv + (long long)t * 6144;
  const float c = cosT[s * 128 + d], sn = sinT[s * 128 + d];
  const int col = h * 128 + d;
  const float SC = 0.08838834764831845f;  // 1/sqrt(128)
  float q1 = bf2f(row[col]), q2 = bf2f(row[col + 64]);
  float k1 = bf2f(row[2048 + col]), k2 = bf2f(row[2048 + col + 64]);
  long long ob = (long long)t * 2048 + col;
  qr[ob] = f2bf((q1 * c - q2 * sn) * SC);
  qr[ob + 64] = f2bf((q2 * c + q1 * sn) * SC);
  kr[ob] = f2bf(k1 * c - k2 * sn);
  kr[ob + 64] = f2bf(k2 * c + k1 * sn);
}

// ---------------- V transpose via LDS tile (coalesced both sides) ----------
__global__ __launch_bounds__(256) void vtrans_k(
    const unsigned short* __restrict__ qkv, unsigned short* __restrict__ vt) {
  __shared__ unsigned short tile[64][66];
  const int tt = blockIdx.x << 6, dd = blockIdx.y << 6;
  const long long b = blockIdx.z;
  const int r0 = threadIdx.x >> 4, c0 = (threadIdx.x & 15) << 2;
#pragma unroll
  for (int i = 0; i < 4; ++i) {
    const int row = r0 + i * 16;
    ushort4 v = *(const ushort4*)&qkv[(b * 2048 + tt + row) * 6144 + 4096 + dd + c0];
    tile[row][c0] = v.x; tile[row][c0 + 1] = v.y;
    tile[row][c0 + 2] = v.z; tile[row][c0 + 3] = v.w;
  }
  __syncthreads();
#pragma unroll
  for (int i = 0; i < 4; ++i) {
    const int d = r0 + i * 16;
    ushort4 o;
    o.x = tile[c0][d]; o.y = tile[c0 + 1][d];
    o.z = tile[c0 + 2][d]; o.w = tile[c0 + 3][d];
    *(ushort4*)&vt[(b * 2048 + dd + d) * 2048 + tt + c0] = o;
  }
}

// ---------------- causal row softmax (single global read, regs) ----------------
__global__ __launch_bounds__(256) void softmax_causal(
    const float* __restrict__ scores, unsigned short* __restrict__ probs) {
  const int r = blockIdx.x;
  const int s = r & 2047;
  const float* src = scores + (long long)r * 2048;
  unsigned short* dst = probs + (long long)r * 2048;
  const int L = s + 1;
  const int j0 = threadIdx.x * 8;
  float4 a = *(const float4*)(src + j0);
  float4 b = *(const float4*)(src + j0 + 4);
  float v[8] = {a.x, a.y, a.z, a.w, b.x, b.y, b.z, b.w};
  float mx = -1e30f;
#pragma unroll
  for (int i = 0; i < 8; ++i) {
    if (j0 + i >= L) v[i] = -1e30f;
    mx = fmaxf(mx, v[i]);
  }
#pragma unroll
  for (int m = 1; m < 64; m <<= 1) mx = fmaxf(mx, __shfl_xor(mx, m));
  __shared__ float redM[4], redS[4];
  if ((threadIdx.x & 63) == 0) redM[threadIdx.x >> 6] = mx;
  __syncthreads();
  mx = fmaxf(fmaxf(redM[0], redM[1]), fmaxf(redM[2], redM[3]));
  float sum = 0.f;
#pragma unroll
  for (int i = 0; i < 8; ++i) {
    v[i] = (j0 + i < L) ? __expf(v[i] - mx) : 0.f;
    sum += v[i];
  }
#pragma unroll
  for (int m = 1; m < 64; m <<= 1) sum += __shfl_xor(sum, m);
  if ((threadIdx.x & 63) == 0) redS[threadIdx.x >> 6] = sum;
  __syncthreads();
  const float inv = 1.f / (redS[0] + redS[1] + redS[2] + redS[3]);
  ushort4 o1, o2;
  o1.x = f2bf(v[0] * inv); o1.y = f2bf(v[1] * inv);
  o1.z = f2bf(v[2] * inv); o1.w = f2bf(v[3] * inv);
  o2.x = f2bf(v[4] * inv); o2.y = f2bf(v[5] * inv);
  o2.z = f2bf(v[6] * inv); o2.w = f2bf(v[7] * inv);
  *(ushort4*)(dst + j0) = o1;
  *(ushort4*)(dst + j0 + 4) = o2;
}

// ------- 128^2 NT GEMM for attention QK/PV (4 blocks/CU, short K-path) -------
template <int EPI, int CAUSAL>
__global__ __launch_bounds__(256) void gemm_nt(
    const unsigned short* __restrict__ A, const unsigned short* __restrict__ Bw,
    void* __restrict__ Cp, int M, int N, int K,
    long long sAz, long long sBz, long long sCz) {
  const long long m0 = (long long)blockIdx.y * 128;
  const long long n0 = (long long)blockIdx.x * 128;
  if (CAUSAL == 1 && n0 > m0 + 127) return;
  __shared__ __align__(16) unsigned short sA[2][128 * 32];
  __shared__ __align__(16) unsigned short sB[2][128 * 32];
  const int tid = threadIdx.x;
  const int w = tid >> 6, l = tid & 63;
  const long long z = blockIdx.z;
  A += z * sAz;
  Bw += z * sBz;
  const long long cofs = z * sCz;
  const int wr = w >> 1, wc = w & 1;
  const int lrow = l & 15, lk = (l >> 4) * 8;

  f32x4 acc[4][4] = {};
  int nk = K >> 5;
  if (CAUSAL == 2) nk = (int)((m0 + 128) >> 5);
  int cur = 0;

  auto stage = [&](int buf, int k0) {
#pragma unroll
    for (int i = 0; i < 2; ++i) {
      const int flat = (w * 2 + i) * 64 + l;
      const int row = flat >> 2;
      const int col = (flat & 3) * 8;
      gload_lds16(&A[(m0 + row) * K + k0 + col], (char*)&sA[buf][0] + (w * 2 + i) * 1024);
      gload_lds16(&Bw[(n0 + row) * K + k0 + col], (char*)&sB[buf][0] + (w * 2 + i) * 1024);
    }
  };

  stage(0, 0);
  __syncthreads();
  for (int kt = 0; kt < nk; ++kt) {
    if (kt + 1 < nk) stage(cur ^ 1, (kt + 1) << 5);
    short8 af[4], bfr[4];
#pragma unroll
    for (int m = 0; m < 4; ++m)
      af[m] = *(const short8*)&sA[cur][(wr * 64 + m * 16 + lrow) * 32 + lk];
#pragma unroll
    for (int n = 0; n < 4; ++n)
      bfr[n] = *(const short8*)&sB[cur][(wc * 64 + n * 16 + lrow) * 32 + lk];
#pragma unroll
    for (int m = 0; m < 4; ++m)
#pragma unroll
      for (int n = 0; n < 4; ++n)
        acc[m][n] = mfma16(af[m], bfr[n], acc[m][n]);
    __syncthreads();
    cur ^= 1;
  }

  const int orow = (l >> 4) * 4, ocol = l & 15;
#pragma unroll
  for (int m = 0; m < 4; ++m)
#pragma unroll
    for (int n = 0; n < 4; ++n)
#pragma unroll
      for (int r = 0; r < 4; ++r) {
        long long gr = m0 + wr * 64 + m * 16 + orow + r;
        long long gc = n0 + wc * 64 + n * 16 + ocol;
        long long idx = cofs + gr * N + gc;
        float v = acc[m][n][r];
        if (EPI == 0) ((unsigned short*)Cp)[idx] = f2bf(v);
        else ((float*)Cp)[idx] = v;
      }
}

// ---------------- 256^2 NT GEMM: 4-phase K-tile schedule (m201-style) --------
// 8 waves (2Mx4N), wave tile 128x64 as 8m x 4n frags of 16x16. K-tile = 64
// split into 2 k-halves of 32. LDS [2buf][A,B][2 khalf][256 rows x 64B] =
// 128KB; swizzle LDS[r][w] = global[r][w ^ ((r>>1)&3)] (PMC-verified
// 0-conflict geometry). Per tile: 4 phases of {ds_reads, stage-issue,
// barrier, lgkmcnt(0)+sched_barrier, setprio(1), 16 MFMA, setprio(0),
// barrier}. ALL of tile t+1 staged during tile t's phases 0-1, so the
// boundary vmcnt(0) drains loads >= 2 phases old (near-free) and buffer t+1
// is never read while written — race-free by construction.
// NT even at every call site (32/16/32/64).
// EPI 0: bf16. 2: bf16 = Ep(bf16)*acc. 4: f32 raw at +z*zCout.
template <int EPI>
__global__ __launch_bounds__(512, 2) void gemm256(
    const unsigned short* __restrict__ A, const unsigned short* __restrict__ Bw,
    void* __restrict__ Cp, const void* __restrict__ Ep,
    int N, int K, int nbx, int kLen, int NT,
    long long sAz, long long sBz, long long zCout) {
  __shared__ __align__(16) unsigned short lds[2 * 2 * 2 * 8192];  // 128KB
  const int tid = threadIdx.x;
  const int wid = tid >> 6, l = tid & 63;
  const int wr = wid >> 2, wcn = wid & 3;

  // 2D-brick XCD schedule (4x8 block bricks per 32 consecutive lin ids)
  const int nwg = gridDim.x;
  const int q8 = nwg >> 3;
  const int lin = (blockIdx.x & 7) * q8 + (blockIdx.x >> 3);
  const int t32 = lin >> 5, r32 = lin & 31;
  const int tpr = nbx >> 3;
  const int tm = t32 / tpr, tn = t32 - tm * tpr;
  const long long m0 = (long long)(tm * 4 + (r32 >> 3)) * 256;
  const long long n0 = (long long)(tn * 8 + (r32 & 7)) * 256;
  const int z = blockIdx.z;
  A += z * sAz;
  Bw += z * sBz;
  const long long kbase = (long long)z * kLen;
  const long long zofs = (long long)z * zCout;

  // staging: one half-tile (mat x khalf) = 256 rows x 32 cols = 16KB,
  // 2 loads/thread. sRow = tid>>2, window = tid&3, pre-swizzled source col.
  const int sRow = tid >> 2;
  const int sCol = ((tid & 3) ^ ((sRow >> 1) & 3)) * 8;
  auto stageH = [&](int tile, int matofs, int khalf, int bufofs) {
    if (tile < NT) {
      const unsigned short* src = matofs ? Bw : A;
      const long long rb = matofs ? n0 : m0;
      const long long kc = kbase + (long long)tile * 64 + khalf * 32 + sCol;
      char* dst = (char*)lds + bufofs + matofs + khalf * 16384 + wid * 1024;
      gload_lds16(&src[(rb + sRow) * K + kc], dst);
      gload_lds16(&src[(rb + sRow + 128) * K + kc], dst + 8192);
    }
  };

  // frag read: row = base + (l&15), window = (l>>4) ^ ((row>>1)&3)
  const int ar = l & 15;
  const int rj = ((l >> 4) ^ ((l >> 1) & 3)) << 4;

  f32x4 acc[8][4] = {};

  // prologue: stage all of tile 0 into buffer 0
  stageH(0, 0, 0, 0); stageH(0, 32768, 0, 0);
  stageH(0, 0, 1, 0); stageH(0, 32768, 1, 0);
  asm volatile("s_waitcnt vmcnt(0)" ::: "memory");
  __builtin_amdgcn_s_barrier();

#define PHASE_SYNC()                                                           \
  __builtin_amdgcn_s_barrier();                                                \
  asm volatile("s_waitcnt lgkmcnt(0)" ::: "memory");                           \
  __builtin_amdgcn_sched_barrier(0);                                           \
  __builtin_amdgcn_s_setprio(1);

#define PHASE_END()                                                            \
  __builtin_amdgcn_s_setprio(0);                                               \
  __builtin_amdgcn_s_barrier();

#define TILE(BUF, tt)                                                          \
  {                                                                            \
    const char* A0 = (const char*)lds + BUF * 65536;                           \
    const char* A1 = A0 + 16384;                                               \
    const char* B0 = A0 + 32768;                                               \
    const char* B1 = A0 + 49152;                                               \
    const int NB = (BUF ^ 1) * 65536;                                          \
    short8 av[4], bv[4];                                                       \
    /* p0: m0-3 x n0-3, k-half 0; stage t+1 k-half 0 */                        \
    _Pragma("unroll") for (int m = 0; m < 4; ++m)                              \
        av[m] = *(const short8*)(A0 + (wr * 128 + m * 16 + ar) * 64 + rj);     \
    _Pragma("unroll") for (int n = 0; n < 4; ++n)                              \
        bv[n] = *(const short8*)(B0 + (wcn * 64 + n * 16 + ar) * 64 + rj);     \
    stageH((tt) + 1, 0, 0, NB);                                                \
    stageH((tt) + 1, 32768, 0, NB);                                            \
    PHASE_SYNC();                                                              \
    _Pragma("unroll") for (int m = 0; m < 4; ++m)                              \
      _Pragma("unroll") for (int n = 0; n < 4; ++n)                            \
          acc[m][n] = mfma16(av[m], bv[n], acc[m][n]);                         \
    PHASE_END();                                                               \
    /* p1: m4-7 x n0-3, k-half 0 (B reused); stage t+1 k-half 1 */             \
    _Pragma("unroll") for (int m = 0; m < 4; ++m)                              \
        av[m] = *(const short8*)(A0 + (wr * 128 + (m + 4) * 16 + ar) * 64 + rj); \
    stageH((tt) + 1, 0, 1, NB);                                                \
    stageH((tt) + 1, 32768, 1, NB);                                            \
    PHASE_SYNC();                                                              \
    _Pragma("unroll") for (int m = 0; m < 4; ++m)                              \
      _Pragma("unroll") for (int n = 0; n < 4; ++n)                            \
          acc[m + 4][n] = mfma16(av[m], bv[n], acc[m + 4][n]);                 \
    PHASE_END();                                                               \
    /* p2: m0-3 x n0-3, k-half 1 */                                            \
    _Pragma("unroll") for (int m = 0; m < 4; ++m)                              \
        av[m] = *(const short8*)(A1 + (wr * 128 + m * 16 + ar) * 64 + rj);     \
    _Pragma("unroll") for (int n = 0; n < 4; ++n)                              \
        bv[n] = *(const short8*)(B1 + (wcn * 64 + n * 16 + ar) * 64 + rj);     \
    PHASE_SYNC();                                                              \
    _Pragma("unroll") for (int m = 0; m < 4; ++m)                              \
      _Pragma("unroll") for (int n = 0; n < 4; ++n)                            \
          acc[m][n] = mfma16(av[m], bv[n], acc[m][n]);                         \
    PHASE_END();                                                               \
    /* p3: m4-7 x n0-3, k-half 1; boundary vmcnt(0) on >=2-phase-old loads */  \
    _Pragma("unroll") for (int m = 0; m < 4; ++m)                              \
        av[m] = *(const short8*)(A1 + (wr * 128 + (m + 4) * 16 + ar) * 64 + rj); \
    PHASE_SYNC();                                                              \
    _Pragma("unroll") for (int m = 0; m < 4; ++m)                              \
      _Pragma("unroll") for (int n = 0; n < 4; ++n)                            \
          acc[m + 4][n] = mfma16(av[m], bv[n], acc[m + 4][n]);                 \
    __builtin_amdgcn_s_setprio(0);                                             \
    asm volatile("s_waitcnt vmcnt(0)" ::: "memory");                           \
    __builtin_amdgcn_s_barrier();                                              \
  }

  for (int t = 0; t < NT; t += 2) {
    TILE(0, t);
    TILE(1, t + 1);
  }
#undef TILE
#undef PHASE_SYNC
#undef PHASE_END

  const int orow = (l >> 4) * 4, ocol = l & 15;
#pragma unroll
  for (int m = 0; m < 8; ++m)
#pragma unroll
    for (int n = 0; n < 4; ++n)
#pragma unroll
      for (int r = 0; r < 4; ++r) {
        const long long gr = m0 + wr * 128 + m * 16 + orow + r;
        const long long gc = n0 + wcn * 64 + n * 16 + ocol;
        const long long idx = zofs + gr * N + gc;
        const float v = acc[m][n][r];
        if (EPI == 0) {
          ((unsigned short*)Cp)[idx] = f2bf(v);
        } else if (EPI == 2) {
          ((unsigned short*)Cp)[idx] = f2bf(bf2f(((const unsigned short*)Ep)[idx]) * v);
        } else {
          ((float*)Cp)[idx] = v;
        }
      }
}

extern "C" void kernel_launch(void* const* d_in, const int* in_sizes, int n_in,
                              void* d_out, int out_size, void* d_ws, size_t ws_size,
                              hipStream_t stream) {
  (void)in_sizes; (void)n_in; (void)out_size; (void)ws_size;
  const float* hidden = (const float*)d_in[0];
  const float* cosT = (const float*)d_in[2];
  const float* sinT = (const float*)d_in[3];
  const float* wq = (const float*)d_in[4];
  const float* wk = (const float*)d_in[5];
  const float* wv = (const float*)d_in[6];
  const float* wo = (const float*)d_in[7];
  const float* wg = (const float*)d_in[8];
  const float* wu = (const float*)d_in[9];
  const float* wd = (const float*)d_in[10];
  const float* ln1 = (const float*)d_in[11];
  const float* ln2 = (const float*)d_in[12];

  const size_t MB = 1ull << 20;
  char* ws = (char*)d_ws;
  unsigned short* xn    = (unsigned short*)(ws + 0);        // 16MB
  unsigned short* wqkvq = (unsigned short*)(ws + 16 * MB);  // 24MB
  unsigned short* qkv   = (unsigned short*)(ws + 40 * MB);  // 48MB
  unsigned short* qrb   = (unsigned short*)(ws + 88 * MB);  // 16MB
  unsigned short* krb   = (unsigned short*)(ws + 104 * MB); // 16MB
  unsigned short* vtb   = (unsigned short*)(ws + 120 * MB); // 16MB
  float*          scoresB = (float*)(ws + 0);               // 32MB alias
  unsigned short* probsB  = (unsigned short*)(ws + 40 * MB);// 16MB alias
  unsigned short* partb = (unsigned short*)(ws + 0);        // 32MB alias
  unsigned short* wgq   = (unsigned short*)(ws + 0);        // 32MB alias
  unsigned short* wuq   = (unsigned short*)(ws + 32 * MB);  // 32MB alias
  unsigned short* gbuf  = (unsigned short*)(ws + 64 * MB);  // 64MB alias
  unsigned short* attnb = (unsigned short*)(ws + 136 * MB); // 16MB
  unsigned short* woq   = (unsigned short*)(ws + 152 * MB); // 8MB
  float*          hbuf  = (float*)(ws + 160 * MB);          // 32MB
  unsigned short* ybuf  = (unsigned short*)(ws + 192 * MB); // 16MB
  unsigned short* gated = (unsigned short*)(ws + 208 * MB); // 64MB
  unsigned short* wdq   = (unsigned short*)(ws + 272 * MB); // 32MB
  float* wspart         = (float*)(ws + 304 * MB);          // 28KB
  float* scales         = (float*)(ws + 304 * MB + 32768);

  // --- scales ---
  MArgs am;
  am.src[0] = wq; am.src[1] = wk; am.src[2] = wv; am.src[3] = wo;
  am.src[4] = wg; am.src[5] = wu; am.src[6] = wd;
  am.n[0] = am.n[1] = am.n[2] = am.n[3] = 4194304;
  am.n[4] = am.n[5] = am.n[6] = 16777216;
  for (int i = 0; i < 7; ++i) { am.dst[i] = nullptr; am.sidx[i] = i; }
  absmean_partial_multi<<<dim3(1024, 7), 256, 0, stream>>>(am, wspart);
  absmean_final<<<7, 256, 0, stream>>>(wspart, scales);

  // --- early quantize: wq,wk,wv,wo,wd ---
  MArgs qe;
  qe.src[0] = wq; qe.dst[0] = wqkvq;            qe.n[0] = 4194304;  qe.sidx[0] = 0;
  qe.src[1] = wk; qe.dst[1] = wqkvq + 4194304;  qe.n[1] = 4194304;  qe.sidx[1] = 1;
  qe.src[2] = wv; qe.dst[2] = wqkvq + 8388608;  qe.n[2] = 4194304;  qe.sidx[2] = 2;
  qe.src[3] = wo; qe.dst[3] = woq;              qe.n[3] = 4194304;  qe.sidx[3] = 3;
  qe.src[4] = wd; qe.dst[4] = wdq;              qe.n[4] = 16777216; qe.sidx[4] = 6;
  qe.src[5] = wq; qe.dst[5] = nullptr; qe.n[5] = 0; qe.sidx[5] = 0;
  qe.src[6] = wq; qe.dst[6] = nullptr; qe.n[6] = 0; qe.sidx[6] = 0;
  quantize_multi<<<dim3(2048, 5), 256, 0, stream>>>(qe, scales);

  rmsnorm_k<<<4096, 256, 0, stream>>>(hidden, ln1, xn);

  // QKV: [4096x6144x2048], grid 384, NT=32
  gemm256<0><<<dim3(384, 1, 1), 512, 0, stream>>>(
      xn, wqkvq, qkv, nullptr, 6144, 2048, 24, 2048, 32, 0, 0, 0);

  rope_k<<<16384, 256, 0, stream>>>(qkv, cosT, sinT, qrb, krb);
  vtrans_k<<<dim3(32, 32, 2), 256, 0, stream>>>(qkv, vtb);

  // attention on 128^2 gemm_nt (4 blocks/CU, short per-block K path)
  gemm_nt<4, 1><<<dim3(16, 16, 2), 256, 0, stream>>>(
      qrb, krb, scoresB, 2048, 2048, 2048, 4194304, 4194304, 4194304);
  softmax_causal<<<4096, 256, 0, stream>>>(scoresB, probsB);
  gemm_nt<0, 2><<<dim3(16, 16, 2), 256, 0, stream>>>(
      probsB, vtb, attnb, 2048, 2048, 2048, 4194304, 4194304, 4194304);

  // O-proj: split-K=2 bf16 partials -> fused combine + ln2 RMSNorm
  gemm256<0><<<dim3(128, 1, 2), 512, 0, stream>>>(
      attnb, woq, partb, nullptr, 2048, 2048, 8, 1024, 16, 0, 0, 8388608);
  combine_rms<<<4096, 256, 0, stream>>>(hidden, partb, ln2, hbuf, ybuf);

  // late quantize: wg, wu
  MArgs ql;
  ql.src[0] = wg; ql.dst[0] = wgq; ql.n[0] = 16777216; ql.sidx[0] = 4;
  ql.src[1] = wu; ql.dst[1] = wuq; ql.n[1] = 16777216; ql.sidx[1] = 5;
  for (int i = 2; i < 7; ++i) { ql.src[i] = wg; ql.dst[i] = nullptr; ql.n[i] = 0; ql.sidx[i] = 0; }
  quantize_multi<<<dim3(2048, 2), 256, 0, stream>>>(ql, scales);

  // G, U: [4096x8192x2048], grid 512, NT=32
  gemm256<0><<<dim3(512, 1, 1), 512, 0, stream>>>(
      ybuf, wgq, gbuf, nullptr, 8192, 2048, 32, 2048, 32, 0, 0, 0);
  gemm256<2><<<dim3(512, 1, 1), 512, 0, stream>>>(
      ybuf, wuq, gated, gbuf, 8192, 2048, 32, 2048, 32, 0, 0, 0);

  // D: [4096x2048x8192] split-K=2 bf16 partials -> combine into d_out
  gemm256<0><<<dim3(128, 1, 2), 512, 0, stream>>>(
      gated, wdq, partb, nullptr, 2048, 8192, 8, 4096, 64, 0, 0, 8388608);
  combine2<<<4096, 256, 0, stream>>>(hbuf, partb, (float*)d_out);
}

// Round 13
// 769.752 us; speedup vs baseline: 1.1323x; 1.1323x over previous
//
#include <hip/hip_runtime.h>
#include <stdint.h>

#define DEV __device__ __forceinline__

typedef __attribute__((ext_vector_type(8))) short short8;
typedef __attribute__((ext_vector_type(8))) __bf16 bf16x8;
typedef __attribute__((ext_vector_type(4))) float f32x4;

DEV unsigned short f2bf(float f) {
  union { float f; unsigned int u; } v; v.f = f;
  unsigned int r = v.u + 0x7fffu + ((v.u >> 16) & 1u);
  return (unsigned short)(r >> 16);
}
DEV float bf2f(unsigned short h) {
  union { unsigned int u; float f; } v; v.u = ((unsigned int)h) << 16;
  return v.f;
}
DEV f32x4 mfma16(short8 a, short8 b, f32x4 c) {
  return __builtin_amdgcn_mfma_f32_16x16x32_bf16(
      __builtin_bit_cast(bf16x8, a), __builtin_bit_cast(bf16x8, b), c, 0, 0, 0);
}
DEV void gload_lds16(const void* g, void* lds) {
  __builtin_amdgcn_global_load_lds(
      (const __attribute__((address_space(1))) void*)g,
      (__attribute__((address_space(3))) void*)lds, 16, 0, 0);
}

struct MArgs {
  const float* src[7];
  unsigned short* dst[7];
  int n[7];
  int sidx[7];
};

// ---------------- abs-mean partial (all matrices, one launch) ----------------
__global__ __launch_bounds__(256) void absmean_partial_multi(
    MArgs a, float* __restrict__ partial) {
  const int m = blockIdx.y;
  const float4* w4 = (const float4*)a.src[m];
  const int n4 = a.n[m] >> 2;
  float s = 0.f;
  for (int i = blockIdx.x * 256 + threadIdx.x; i < n4; i += 1024 * 256) {
    float4 v = w4[i];
    s += fabsf(v.x) + fabsf(v.y) + fabsf(v.z) + fabsf(v.w);
  }
#pragma unroll
  for (int mm = 1; mm < 64; mm <<= 1) s += __shfl_xor(s, mm);
  __shared__ float red[4];
  if ((threadIdx.x & 63) == 0) red[threadIdx.x >> 6] = s;
  __syncthreads();
  if (threadIdx.x == 0)
    partial[m * 1024 + blockIdx.x] = red[0] + red[1] + red[2] + red[3];
}

__global__ __launch_bounds__(256) void absmean_final(
    const float* __restrict__ partial, float* __restrict__ scales) {
  __shared__ double red[256];
  const int m = blockIdx.x;
  double s = 0.0;
  for (int i = threadIdx.x; i < 1024; i += 256) s += (double)partial[m * 1024 + i];
  red[threadIdx.x] = s;
  __syncthreads();
  for (int t = 128; t > 0; t >>= 1) {
    if (threadIdx.x < t) red[threadIdx.x] += red[threadIdx.x + t];
    __syncthreads();
  }
  if (threadIdx.x == 0) {
    const long long cnt = (m < 4) ? 4194304ll : 16777216ll;
    scales[m] = (float)(red[0] / (double)cnt);
  }
}

// ---------------- ternary quantize -> bf16 (batched) ----------------
__global__ __launch_bounds__(256) void quantize_multi(
    MArgs a, const float* __restrict__ scales) {
  const int m = blockIdx.y;
  const float sc = scales[a.sidx[m]];
  const float inv = 1.f / (sc + 1e-5f);
  const float4* src = (const float4*)a.src[m];
  ushort4* dst = (ushort4*)a.dst[m];
  const int n4 = a.n[m] >> 2;
  for (int i = blockIdx.x * 256 + threadIdx.x; i < n4; i += 2048 * 256) {
    float4 v = src[i];
    ushort4 o;
    o.x = f2bf(fminf(fmaxf(rintf(v.x * inv), -1.f), 1.f) * sc);
    o.y = f2bf(fminf(fmaxf(rintf(v.y * inv), -1.f), 1.f) * sc);
    o.z = f2bf(fminf(fmaxf(rintf(v.z * inv), -1.f), 1.f) * sc);
    o.w = f2bf(fminf(fmaxf(rintf(v.w * inv), -1.f), 1.f) * sc);
    dst[i] = o;
  }
}

// ---------------- RMSNorm (f32 in -> bf16 out) ----------------
__global__ __launch_bounds__(256) void rmsnorm_k(
    const float* __restrict__ x, const float* __restrict__ wt,
    unsigned short* __restrict__ out) {
  const long long t = blockIdx.x;
  const float* xr = x + t * 2048;
  const int i0 = threadIdx.x * 8;
  float4 a = *(const float4*)(xr + i0);
  float4 b = *(const float4*)(xr + i0 + 4);
  float ss = a.x * a.x + a.y * a.y + a.z * a.z + a.w * a.w +
             b.x * b.x + b.y * b.y + b.z * b.z + b.w * b.w;
#pragma unroll
  for (int m = 1; m < 64; m <<= 1) ss += __shfl_xor(ss, m);
  __shared__ float red[4];
  if ((threadIdx.x & 63) == 0) red[threadIdx.x >> 6] = ss;
  __syncthreads();
  float tot = red[0] + red[1] + red[2] + red[3];
  float rs = rsqrtf(tot * (1.f / 2048.f) + 1e-5f);
  float4 wa = *(const float4*)(wt + i0);
  float4 wb = *(const float4*)(wt + i0 + 4);
  ushort4 o1, o2;
  o1.x = f2bf(a.x * wa.x * rs); o1.y = f2bf(a.y * wa.y * rs);
  o1.z = f2bf(a.z * wa.z * rs); o1.w = f2bf(a.w * wa.w * rs);
  o2.x = f2bf(b.x * wb.x * rs); o2.y = f2bf(b.y * wb.y * rs);
  o2.z = f2bf(b.z * wb.z * rs); o2.w = f2bf(b.w * wb.w * rs);
  *(ushort4*)(out + t * 2048 + i0) = o1;
  *(ushort4*)(out + t * 2048 + i0 + 4) = o2;
}

// ---- fused O-combine + RMSNorm(ln2), bf16 split-K partials ----
__global__ __launch_bounds__(256) void combine_rms(
    const float* __restrict__ ep, const unsigned short* __restrict__ p,
    const float* __restrict__ wt, float* __restrict__ hout,
    unsigned short* __restrict__ yout) {
  const long long t = blockIdx.x;
  const int i0 = threadIdx.x * 8;
  const long long base = t * 2048 + i0;
  float4 e1 = *(const float4*)(ep + base);
  float4 e2 = *(const float4*)(ep + base + 4);
  short8 pa = *(const short8*)(p + base);
  short8 pb = *(const short8*)(p + 8388608 + base);
  const float e[8] = {e1.x, e1.y, e1.z, e1.w, e2.x, e2.y, e2.z, e2.w};
  float h[8];
#pragma unroll
  for (int i = 0; i < 8; ++i)
    h[i] = e[i] + bf2f((unsigned short)pa[i]) + bf2f((unsigned short)pb[i]);
  float4 h1 = {h[0], h[1], h[2], h[3]};
  float4 h2 = {h[4], h[5], h[6], h[7]};
  *(float4*)(hout + base) = h1;
  *(float4*)(hout + base + 4) = h2;
  float ss = 0.f;
#pragma unroll
  for (int i = 0; i < 8; ++i) ss += h[i] * h[i];
#pragma unroll
  for (int m = 1; m < 64; m <<= 1) ss += __shfl_xor(ss, m);
  __shared__ float red[4];
  if ((threadIdx.x & 63) == 0) red[threadIdx.x >> 6] = ss;
  __syncthreads();
  const float tot = red[0] + red[1] + red[2] + red[3];
  const float rs = rsqrtf(tot * (1.f / 2048.f) + 1e-5f);
  float4 wa = *(const float4*)(wt + i0);
  float4 wb = *(const float4*)(wt + i0 + 4);
  ushort4 o1, o2;
  o1.x = f2bf(h[0] * wa.x * rs); o1.y = f2bf(h[1] * wa.y * rs);
  o1.z = f2bf(h[2] * wa.z * rs); o1.w = f2bf(h[3] * wa.w * rs);
  o2.x = f2bf(h[4] * wb.x * rs); o2.y = f2bf(h[5] * wb.y * rs);
  o2.z = f2bf(h[6] * wb.z * rs); o2.w = f2bf(h[7] * wb.w * rs);
  *(ushort4*)(yout + base) = o1;
  *(ushort4*)(yout + base + 4) = o2;
}

// ---- D-combine, bf16 partials: out = ep + p0 + p1 ----
__global__ __launch_bounds__(256) void combine2(
    const float* __restrict__ ep, const unsigned short* __restrict__ p,
    float* __restrict__ out) {
  const long long base = (long long)blockIdx.x * 2048 + threadIdx.x * 8;
  float4 e1 = *(const float4*)(ep + base);
  float4 e2 = *(const float4*)(ep + base + 4);
  short8 pa = *(const short8*)(p + base);
  short8 pb = *(const short8*)(p + 8388608 + base);
  float4 o1, o2;
  o1.x = e1.x + bf2f((unsigned short)pa[0]) + bf2f((unsigned short)pb[0]);
  o1.y = e1.y + bf2f((unsigned short)pa[1]) + bf2f((unsigned short)pb[1]);
  o1.z = e1.z + bf2f((unsigned short)pa[2]) + bf2f((unsigned short)pb[2]);
  o1.w = e1.w + bf2f((unsigned short)pa[3]) + bf2f((unsigned short)pb[3]);
  o2.x = e2.x + bf2f((unsigned short)pa[4]) + bf2f((unsigned short)pb[4]);
  o2.y = e2.y + bf2f((unsigned short)pa[5]) + bf2f((unsigned short)pb[5]);
  o2.z = e2.z + bf2f((unsigned short)pa[6]) + bf2f((unsigned short)pb[6]);
  o2.w = e2.w + bf2f((unsigned short)pa[7]) + bf2f((unsigned short)pb[7]);
  *(float4*)(out + base) = o1;
  *(float4*)(out + base + 4) = o2;
}

// ---------------- RoPE (q,k only; V handled by vtrans_k) ----------------
__global__ __launch_bounds__(256) void rope_k(
    const unsigned short* __restrict__ qkv, const float* __restrict__ cosT,
    const float* __restrict__ sinT, unsigned short* __restrict__ qr,
    unsigned short* __restrict__ kr) {
  const long long gid = (long long)blockIdx.x * 256 + threadIdx.x;
  const int t = (int)(gid >> 10);
  const int r = (int)(gid & 1023);
  const int h = r >> 6, d = r & 63;
  const int s = t & 2047;
  const unsigned short* row = qkv + (long long)t * 6144;
  const float c = cosT[s * 128 + d], sn = sinT[s * 128 + d];
  const int col = h * 128 + d;
  const float SC = 0.08838834764831845f;  // 1/sqrt(128)
  float q1 = bf2f(row[col]), q2 = bf2f(row[col + 64]);
  float k1 = bf2f(row[2048 + col]), k2 = bf2f(row[2048 + col + 64]);
  long long ob = (long long)t * 2048 + col;
  qr[ob] = f2bf((q1 * c - q2 * sn) * SC);
  qr[ob + 64] = f2bf((q2 * c + q1 * sn) * SC);
  kr[ob] = f2bf(k1 * c - k2 * sn);
  kr[ob + 64] = f2bf(k2 * c + k1 * sn);
}

// ---------------- V transpose via LDS tile (coalesced both sides) ----------
__global__ __launch_bounds__(256) void vtrans_k(
    const unsigned short* __restrict__ qkv, unsigned short* __restrict__ vt) {
  __shared__ unsigned short tile[64][66];
  const int tt = blockIdx.x << 6, dd = blockIdx.y << 6;
  const long long b = blockIdx.z;
  const int r0 = threadIdx.x >> 4, c0 = (threadIdx.x & 15) << 2;
#pragma unroll
  for (int i = 0; i < 4; ++i) {
    const int row = r0 + i * 16;
    ushort4 v = *(const ushort4*)&qkv[(b * 2048 + tt + row) * 6144 + 4096 + dd + c0];
    tile[row][c0] = v.x; tile[row][c0 + 1] = v.y;
    tile[row][c0 + 2] = v.z; tile[row][c0 + 3] = v.w;
  }
  __syncthreads();
#pragma unroll
  for (int i = 0; i < 4; ++i) {
    const int d = r0 + i * 16;
    ushort4 o;
    o.x = tile[c0][d]; o.y = tile[c0 + 1][d];
    o.z = tile[c0 + 2][d]; o.w = tile[c0 + 3][d];
    *(ushort4*)&vt[(b * 2048 + dd + d) * 2048 + tt + c0] = o;
  }
}

// ---------------- causal row softmax (single global read, regs) ----------------
__global__ __launch_bounds__(256) void softmax_causal(
    const float* __restrict__ scores, unsigned short* __restrict__ probs) {
  const int r = blockIdx.x;
  const int s = r & 2047;
  const float* src = scores + (long long)r * 2048;
  unsigned short* dst = probs + (long long)r * 2048;
  const int L = s + 1;
  const int j0 = threadIdx.x * 8;
  float4 a = *(const float4*)(src + j0);
  float4 b = *(const float4*)(src + j0 + 4);
  float v[8] = {a.x, a.y, a.z, a.w, b.x, b.y, b.z, b.w};
  float mx = -1e30f;
#pragma unroll
  for (int i = 0; i < 8; ++i) {
    if (j0 + i >= L) v[i] = -1e30f;
    mx = fmaxf(mx, v[i]);
  }
#pragma unroll
  for (int m = 1; m < 64; m <<= 1) mx = fmaxf(mx, __shfl_xor(mx, m));
  __shared__ float redM[4], redS[4];
  if ((threadIdx.x & 63) == 0) redM[threadIdx.x >> 6] = mx;
  __syncthreads();
  mx = fmaxf(fmaxf(redM[0], redM[1]), fmaxf(redM[2], redM[3]));
  float sum = 0.f;
#pragma unroll
  for (int i = 0; i < 8; ++i) {
    v[i] = (j0 + i < L) ? __expf(v[i] - mx) : 0.f;
    sum += v[i];
  }
#pragma unroll
  for (int m = 1; m < 64; m <<= 1) sum += __shfl_xor(sum, m);
  if ((threadIdx.x & 63) == 0) redS[threadIdx.x >> 6] = sum;
  __syncthreads();
  const float inv = 1.f / (redS[0] + redS[1] + redS[2] + redS[3]);
  ushort4 o1, o2;
  o1.x = f2bf(v[0] * inv); o1.y = f2bf(v[1] * inv);
  o1.z = f2bf(v[2] * inv); o1.w = f2bf(v[3] * inv);
  o2.x = f2bf(v[4] * inv); o2.y = f2bf(v[5] * inv);
  o2.z = f2bf(v[6] * inv); o2.w = f2bf(v[7] * inv);
  *(ushort4*)(dst + j0) = o1;
  *(ushort4*)(dst + j0 + 4) = o2;
}

// ------- 128^2 NT GEMM for attention QK/PV (swizzled LDS, 0-conflict) -------
// Same 64B-row geometry as gemm256: LDS[r][w] = global[r][w ^ ((r>>1)&3)],
// staged linear (dst byte = flat*16), read window rj = (l>>4)^((l>>1)&3).
// EPI 0: bf16 out. 4: f32 raw. CAUSAL 1: skip n0 > m0+127. 2: K-limit.
template <int EPI, int CAUSAL>
__global__ __launch_bounds__(256) void gemm_nt(
    const unsigned short* __restrict__ A, const unsigned short* __restrict__ Bw,
    void* __restrict__ Cp, int M, int N, int K,
    long long sAz, long long sBz, long long sCz) {
  const long long m0 = (long long)blockIdx.y * 128;
  const long long n0 = (long long)blockIdx.x * 128;
  if (CAUSAL == 1 && n0 > m0 + 127) return;
  __shared__ __align__(16) unsigned short sA[2][128 * 32];
  __shared__ __align__(16) unsigned short sB[2][128 * 32];
  const int tid = threadIdx.x;
  const int w = tid >> 6, l = tid & 63;
  const long long z = blockIdx.z;
  A += z * sAz;
  Bw += z * sBz;
  const long long cofs = z * sCz;
  const int wr = w >> 1, wc = w & 1;
  const int lrow = l & 15;
  const int rj = ((l >> 4) ^ ((l >> 1) & 3)) << 4;  // swizzled 16B window

  f32x4 acc[4][4] = {};
  int nk = K >> 5;
  if (CAUSAL == 2) nk = (int)((m0 + 128) >> 5);
  int cur = 0;

  auto stage = [&](int buf, int k0) {
#pragma unroll
    for (int i = 0; i < 2; ++i) {
      const int flat = (w * 2 + i) * 64 + l;
      const int row = flat >> 2;
      const int col = ((flat & 3) ^ ((row >> 1) & 3)) * 8;  // pre-swizzled src
      gload_lds16(&A[(m0 + row) * K + k0 + col], (char*)&sA[buf][0] + (w * 2 + i) * 1024);
      gload_lds16(&Bw[(n0 + row) * K + k0 + col], (char*)&sB[buf][0] + (w * 2 + i) * 1024);
    }
  };

  stage(0, 0);
  __syncthreads();
  for (int kt = 0; kt < nk; ++kt) {
    if (kt + 1 < nk) stage(cur ^ 1, (kt + 1) << 5);
    short8 af[4], bfr[4];
#pragma unroll
    for (int m = 0; m < 4; ++m)
      af[m] = *(const short8*)((char*)&sA[cur][0] + (wr * 64 + m * 16 + lrow) * 64 + rj);
#pragma unroll
    for (int n = 0; n < 4; ++n)
      bfr[n] = *(const short8*)((char*)&sB[cur][0] + (wc * 64 + n * 16 + lrow) * 64 + rj);
#pragma unroll
    for (int m = 0; m < 4; ++m)
#pragma unroll
      for (int n = 0; n < 4; ++n)
        acc[m][n] = mfma16(af[m], bfr[n], acc[m][n]);
    __syncthreads();
    cur ^= 1;
  }

  const int orow = (l >> 4) * 4, ocol = l & 15;
#pragma unroll
  for (int m = 0; m < 4; ++m)
#pragma unroll
    for (int n = 0; n < 4; ++n)
#pragma unroll
      for (int r = 0; r < 4; ++r) {
        long long gr = m0 + wr * 64 + m * 16 + orow + r;
        long long gc = n0 + wc * 64 + n * 16 + ocol;
        long long idx = cofs + gr * N + gc;
        float v = acc[m][n][r];
        if (EPI == 0) ((unsigned short*)Cp)[idx] = f2bf(v);
        else ((float*)Cp)[idx] = v;
      }
}

// ---------------- 256^2 NT GEMM: pipelined, 4-unrolled (round-11 FROZEN) -----
// Best measured schedule (47.5% MfmaUtil): reads 1 phase ahead, counted
// vmcnt(4) rendezvous every 2 chunks, static slots, 0-conflict swizzle,
// brick XCD schedule. See round-9/10 ledger comments.
template <int EPI>
__global__ __launch_bounds__(512, 2) void gemm256(
    const unsigned short* __restrict__ A, const unsigned short* __restrict__ Bw,
    void* __restrict__ Cp, const void* __restrict__ Ep,
    int N, int K, int nbx, int kLen, int ng,
    long long sAz, long long sBz, long long zCout) {
  __shared__ __align__(16) unsigned short lds[4 * 2 * 8192];  // 128KB
  __shared__ __align__(16) unsigned short ldsDummy[512];      // 1KB sink
  const int tid = threadIdx.x;
  const int wid = tid >> 6, l = tid & 63;
  const int wr = wid >> 2, wcn = wid & 3;

  const int nwg = gridDim.x;
  const int q8 = nwg >> 3;
  const int lin = (blockIdx.x & 7) * q8 + (blockIdx.x >> 3);
  const int t32 = lin >> 5, r32 = lin & 31;
  const int tpr = nbx >> 3;
  const int tm = t32 / tpr, tn = t32 - tm * tpr;
  const long long m0 = (long long)(tm * 4 + (r32 >> 3)) * 256;
  const long long n0 = (long long)(tn * 8 + (r32 & 7)) * 256;
  const int z = blockIdx.z;
  A += z * sAz;
  Bw += z * sBz;
  const long long kbase = (long long)z * kLen;
  const long long zofs = (long long)z * zCout;

  const int stRow = (l >> 2);
  const int stCol = (((l & 3) ^ ((l >> 3) & 3))) * 8;
  auto stage = [&](int chunk, int sslot) {
    if (chunk < ng) {
      char* base = (char*)lds + (sslot * 2) * 16384;
      const long long kcol = kbase + (long long)chunk * 32 + stCol;
#pragma unroll
      for (int i = 0; i < 2; ++i) {
        const int row = (wid * 2 + i) * 16 + stRow;
        gload_lds16(&A[(m0 + row) * K + kcol], base + (wid * 2 + i) * 1024);
        gload_lds16(&Bw[(n0 + row) * K + kcol],
                    base + 16384 + (wid * 2 + i) * 1024);
      }
    } else {
#pragma unroll
      for (int i = 0; i < 4; ++i) gload_lds16(&A[m0 * K], (char*)ldsDummy);
    }
  };

  const int ar = l & 15;
  const int rj = ((l >> 4) ^ ((l >> 1) & 3)) << 4;
  const int aoff = (wr * 128 + ar) * 64 + rj;
  const int boff = (wcn * 64 + ar) * 64 + rj;

  f32x4 acc[8][4] = {};
  short8 aX[4], bX[4], aY[4], bY[4];

  stage(0, 0); stage(1, 1); stage(2, 2);
  asm volatile("s_waitcnt vmcnt(4)" ::: "memory");
  __builtin_amdgcn_s_barrier();
#pragma unroll
  for (int m = 0; m < 4; ++m)
    aX[m] = *(const short8*)((const char*)lds + aoff + m * 1024);
#pragma unroll
  for (int n = 0; n < 4; ++n)
    bX[n] = *(const short8*)((const char*)lds + 16384 + boff + n * 1024);

#define CHUNK_BODY(SLOT, NSLOT, SYNC, cur03, curB, nxt03, nxtB, cc)            \
  {                                                                            \
    const char* sAc = (const char*)lds + (SLOT * 2) * 16384;                   \
    const char* sAn = (const char*)lds + (NSLOT * 2) * 16384;                  \
    const char* sBn = (const char*)lds + (NSLOT * 2 + 1) * 16384;              \
    short8 a47[4];                                                             \
    _Pragma("unroll") for (int m = 0; m < 4; ++m)                              \
        a47[m] = *(const short8*)(sAc + aoff + 4096 + m * 1024);               \
    stage((cc) + 3, (SLOT + 3) & 3);                                           \
    __builtin_amdgcn_s_setprio(1);                                             \
    _Pragma("unroll") for (int m = 0; m < 4; ++m)                              \
      _Pragma("unroll") for (int n = 0; n < 4; ++n)                            \
          acc[m][n] = mfma16(cur03[m], curB[n], acc[m][n]);                    \
    __builtin_amdgcn_s_setprio(0);                                             \
    if (SYNC) {                                                                \
      asm volatile("s_waitcnt vmcnt(4)" ::: "memory");                         \
      __builtin_amdgcn_s_barrier();                                            \
    }                                                                          \
    _Pragma("unroll") for (int m = 0; m < 4; ++m)                              \
        nxt03[m] = *(const short8*)(sAn + aoff + m * 1024);                    \
    _Pragma("unroll") for (int n = 0; n < 4; ++n)                              \
        nxtB[n] = *(const short8*)(sBn + boff + n * 1024);                     \
    __builtin_amdgcn_s_setprio(1);                                             \
    _Pragma("unroll") for (int m = 0; m < 4; ++m)                              \
      _Pragma("unroll") for (int n = 0; n < 4; ++n)                            \
          acc[m + 4][n] = mfma16(a47[m], curB[n], acc[m + 4][n]);              \
    __builtin_amdgcn_s_setprio(0);                                             \
  }

  for (int c = 0; c < ng; c += 4) {
    CHUNK_BODY(0, 1, false, aX, bX, aY, bY, c);
    CHUNK_BODY(1, 2, true, aY, bY, aX, bX, c + 1);
    CHUNK_BODY(2, 3, false, aX, bX, aY, bY, c + 2);
    CHUNK_BODY(3, 0, true, aY, bY, aX, bX, c + 3);
  }
#undef CHUNK_BODY
  asm volatile("s_waitcnt vmcnt(0)" ::: "memory");
  __builtin_amdgcn_s_barrier();

  const int orow = (l >> 4) * 4, ocol = l & 15;
#pragma unroll
  for (int m = 0; m < 8; ++m)
#pragma unroll
    for (int n = 0; n < 4; ++n)
#pragma unroll
      for (int r = 0; r < 4; ++r) {
        const long long gr = m0 + wr * 128 + m * 16 + orow + r;
        const long long gc = n0 + wcn * 64 + n * 16 + ocol;
        const long long idx = zofs + gr * N + gc;
        const float v = acc[m][n][r];
        if (EPI == 0) {
          ((unsigned short*)Cp)[idx] = f2bf(v);
        } else if (EPI == 2) {
          ((unsigned short*)Cp)[idx] = f2bf(bf2f(((const unsigned short*)Ep)[idx]) * v);
        } else {
          ((float*)Cp)[idx] = v;
        }
      }
}

extern "C" void kernel_launch(void* const* d_in, const int* in_sizes, int n_in,
                              void* d_out, int out_size, void* d_ws, size_t ws_size,
                              hipStream_t stream) {
  (void)in_sizes; (void)n_in; (void)out_size; (void)ws_size;
  const float* hidden = (const float*)d_in[0];
  const float* cosT = (const float*)d_in[2];
  const float* sinT = (const float*)d_in[3];
  const float* wq = (const float*)d_in[4];
  const float* wk = (const float*)d_in[5];
  const float* wv = (const float*)d_in[6];
  const float* wo = (const float*)d_in[7];
  const float* wg = (const float*)d_in[8];
  const float* wu = (const float*)d_in[9];
  const float* wd = (const float*)d_in[10];
  const float* ln1 = (const float*)d_in[11];
  const float* ln2 = (const float*)d_in[12];

  const size_t MB = 1ull << 20;
  char* ws = (char*)d_ws;
  unsigned short* xn    = (unsigned short*)(ws + 0);        // 16MB
  unsigned short* wqkvq = (unsigned short*)(ws + 16 * MB);  // 24MB
  unsigned short* qkv   = (unsigned short*)(ws + 40 * MB);  // 48MB
  unsigned short* qrb   = (unsigned short*)(ws + 88 * MB);  // 16MB
  unsigned short* krb   = (unsigned short*)(ws + 104 * MB); // 16MB
  unsigned short* vtb   = (unsigned short*)(ws + 120 * MB); // 16MB
  float*          scoresB = (float*)(ws + 0);               // 32MB alias
  unsigned short* probsB  = (unsigned short*)(ws + 40 * MB);// 16MB alias
  unsigned short* partb = (unsigned short*)(ws + 0);        // 32MB alias
  unsigned short* wgq   = (unsigned short*)(ws + 0);        // 32MB alias
  unsigned short* wuq   = (unsigned short*)(ws + 32 * MB);  // 32MB alias
  unsigned short* gbuf  = (unsigned short*)(ws + 64 * MB);  // 64MB alias
  unsigned short* attnb = (unsigned short*)(ws + 136 * MB); // 16MB
  unsigned short* woq   = (unsigned short*)(ws + 152 * MB); // 8MB
  float*          hbuf  = (float*)(ws + 160 * MB);          // 32MB
  unsigned short* ybuf  = (unsigned short*)(ws + 192 * MB); // 16MB
  unsigned short* gated = (unsigned short*)(ws + 208 * MB); // 64MB
  unsigned short* wdq   = (unsigned short*)(ws + 272 * MB); // 32MB
  float* wspart         = (float*)(ws + 304 * MB);          // 28KB
  float* scales         = (float*)(ws + 304 * MB + 32768);

  // --- scales ---
  MArgs am;
  am.src[0] = wq; am.src[1] = wk; am.src[2] = wv; am.src[3] = wo;
  am.src[4] = wg; am.src[5] = wu; am.src[6] = wd;
  am.n[0] = am.n[1] = am.n[2] = am.n[3] = 4194304;
  am.n[4] = am.n[5] = am.n[6] = 16777216;
  for (int i = 0; i < 7; ++i) { am.dst[i] = nullptr; am.sidx[i] = i; }
  absmean_partial_multi<<<dim3(1024, 7), 256, 0, stream>>>(am, wspart);
  absmean_final<<<7, 256, 0, stream>>>(wspart, scales);

  // --- early quantize: wq,wk,wv,wo,wd ---
  MArgs qe;
  qe.src[0] = wq; qe.dst[0] = wqkvq;            qe.n[0] = 4194304;  qe.sidx[0] = 0;
  qe.src[1] = wk; qe.dst[1] = wqkvq + 4194304;  qe.n[1] = 4194304;  qe.sidx[1] = 1;
  qe.src[2] = wv; qe.dst[2] = wqkvq + 8388608;  qe.n[2] = 4194304;  qe.sidx[2] = 2;
  qe.src[3] = wo; qe.dst[3] = woq;              qe.n[3] = 4194304;  qe.sidx[3] = 3;
  qe.src[4] = wd; qe.dst[4] = wdq;              qe.n[4] = 16777216; qe.sidx[4] = 6;
  qe.src[5] = wq; qe.dst[5] = nullptr; qe.n[5] = 0; qe.sidx[5] = 0;
  qe.src[6] = wq; qe.dst[6] = nullptr; qe.n[6] = 0; qe.sidx[6] = 0;
  quantize_multi<<<dim3(2048, 5), 256, 0, stream>>>(qe, scales);

  rmsnorm_k<<<4096, 256, 0, stream>>>(hidden, ln1, xn);

  // QKV: [4096x6144x2048], grid 384, 64 K-chunks
  gemm256<0><<<dim3(384, 1, 1), 512, 0, stream>>>(
      xn, wqkvq, qkv, nullptr, 6144, 2048, 24, 2048, 64, 0, 0, 0);

  rope_k<<<16384, 256, 0, stream>>>(qkv, cosT, sinT, qrb, krb);
  vtrans_k<<<dim3(32, 32, 2), 256, 0, stream>>>(qkv, vtb);

  // attention on 128^2 gemm_nt (4 blocks/CU, short per-block K path)
  gemm_nt<4, 1><<<dim3(16, 16, 2), 256, 0, stream>>>(
      qrb, krb, scoresB, 2048, 2048, 2048, 4194304, 4194304, 4194304);
  softmax_causal<<<4096, 256, 0, stream>>>(scoresB, probsB);
  gemm_nt<0, 2><<<dim3(16, 16, 2), 256, 0, stream>>>(
      probsB, vtb, attnb, 2048, 2048, 2048, 4194304, 4194304, 4194304);

  // O-proj: split-K=2 bf16 partials -> fused combine + ln2 RMSNorm
  gemm256<0><<<dim3(128, 1, 2), 512, 0, stream>>>(
      attnb, woq, partb, nullptr, 2048, 2048, 8, 1024, 32, 0, 0, 8388608);
  combine_rms<<<4096, 256, 0, stream>>>(hidden, partb, ln2, hbuf, ybuf);

  // late quantize: wg, wu
  MArgs ql;
  ql.src[0] = wg; ql.dst[0] = wgq; ql.n[0] = 16777216; ql.sidx[0] = 4;
  ql.src[1] = wu; ql.dst[1] = wuq; ql.n[1] = 16777216; ql.sidx[1] = 5;
  for (int i = 2; i < 7; ++i) { ql.src[i] = wg; ql.dst[i] = nullptr; ql.n[i] = 0; ql.sidx[i] = 0; }
  quantize_multi<<<dim3(2048, 2), 256, 0, stream>>>(ql, scales);

  // G, U: [4096x8192x2048], grid 512, 32 K-chunks... (ng=64 chunks of 32)
  gemm256<0><<<dim3(512, 1, 1), 512, 0, stream>>>(
      ybuf, wgq, gbuf, nullptr, 8192, 2048, 32, 2048, 64, 0, 0, 0);
  gemm256<2><<<dim3(512, 1, 1), 512, 0, stream>>>(
      ybuf, wuq, gated, gbuf, 8192, 2048, 32, 2048, 64, 0, 0, 0);

  // D: [4096x2048x8192] split-K=2 bf16 partials -> combine into d_out
  gemm256<0><<<dim3(128, 1, 2), 512, 0, stream>>>(
      gated, wdq, partb, nullptr, 2048, 8192, 8, 4096, 128, 0, 0, 8388608);
  combine2<<<4096, 256, 0, stream>>>(hbuf, partb, (float*)d_out);
}